// Round 4
// baseline (1377.397 us; speedup 1.0000x reference)
//
#include <hip/hip_runtime.h>
#include <stdint.h>
#include <stddef.h>

// ---------------------------------------------------------------------------
// PCgraph: T=32 steps of
//   mu = tanh(x) @ w^T ; e = (x-mu)*m ; g = e @ w ;
//   x = x - 0.1*m*(e - (1-tanh(x)^2)*g)
// bf16 MFMA 16x16x32, fp32 accum. x state in d_out (fp32).
// Round 13: 128x128 TILES AT CONSTANT WAVE COUNT. Measured invariant
// (r9/r10/r12): staging runs at ~11 TB/s chip-wide iff ~13 waves/CU are
// issuing global_load_lds (~1.4 B/cy/wave); time scales with staged bytes at
// fixed wave count (r12: -10% bytes -> -7% time) and collapses when waves
// drop (r10: 8 waves/CU -> 3.8 TB/s). So: halve the bytes WITHOUT dropping
// waves. 128x128 tiles / 512-thread (8-wave) blocks / KSPLIT=8:
//   416 blocks x 8 waves = 3328 waves = 13/CU  (same as r9/r12)
//   staged bytes per GEMM: 86.5 MB vs r12's 177 MB (A-traffic halves:
//   26 ntile-pairs instead of 52 ntiles re-reading all of A)
//   LDS 64 KB -> 2 blocks/CU; per-wave staging density unchanged (4 KB/iter)
// Keeps r12's mu0 precompute (GEMM1 k = live 3328 only) and XCD-pinned B
// panels (<=4 ntile-pairs x 832 KB = 3.3 MB per XCD L2, map dispatch-stable
// across all 32 steps). Partial slices 4 -> 8 (+13.6 MB/step, small).
// ws end @ 70,254,592 < 256 MiB (fillBuffer WRITE_SIZE=262144 KB = ws size).
// ---------------------------------------------------------------------------

#define N_DIM 4096
#define B_DIM 256
#define T_STEPS 32
#define LR_X 0.1f
#define N0 768                      // first live column (aligned down from 784)
#define N_LIVE 3328                 // 4096 - 768 = 52*64
#define KSPLIT 8
#define NCHL 52                     // live k-chunks (both GEMMs)

typedef unsigned short ushort_t;
using bf16x8 = __attribute__((ext_vector_type(8))) __bf16;
using f32x4  = __attribute__((ext_vector_type(4))) float;

__device__ __forceinline__ ushort_t f2bf(float f) {
    union { float f; unsigned int u; } v; v.f = f;
    unsigned int r = v.u + 0x7fffu + ((v.u >> 16) & 1u);   // RNE
    return (ushort_t)(r >> 16);
}
__device__ __forceinline__ float bf2f(ushort_t h) {
    union { unsigned int u; float f; } v; v.u = ((unsigned int)h) << 16;
    return v.f;
}

// fragment-order index of element (r, c) inside a 64x64 tile-chunk
// (matches the LDS layout the MFMA fragments read; verified rounds 0-12)
__device__ __forceinline__ int pkidx(int r, int c) {
    const int s = ((r >> 4) << 1) | ((c >> 5) & 1);
    return s * 512 + (r & 15) * 8 + (((c >> 3) & 3) << 7) + (c & 7);
}

__device__ __forceinline__ void async_copy16(const ushort_t* g, ushort_t* l) {
    __builtin_amdgcn_global_load_lds(
        (__attribute__((address_space(1))) void*)(g),
        (__attribute__((address_space(3))) void*)(l),
        16, 0, 0);
}

// --- pack w -> w_pk [52 ntile][64 chunk][4096]  (B of GEMM1: rows 768..4095)
//            -> wt_pk [52 ntile][52 chunk][4096] (B of GEMM2: w^T, live range)
__global__ __launch_bounds__(256) void pack_w(const float* __restrict__ w,
                                              ushort_t* __restrict__ wpk,
                                              ushort_t* __restrict__ wtpk) {
    __shared__ float tile[64][68];
    const int tid = threadIdx.x;
    const int bid = blockIdx.x;
    int row0, col0; ushort_t* dst; bool tr;
    if (bid < 52 * 64) {
        tr   = false;
        dst  = wpk + (size_t)bid * 4096;
        row0 = N0 + (bid >> 6) * 64;      // B-row (n) block
        col0 = (bid & 63) * 64;           // k block
    } else {
        const int b2 = bid - 52 * 64;
        tr   = true;
        dst  = wtpk + (size_t)b2 * 4096;
        const int ntile = b2 / 52, chunk = b2 - ntile * 52;
        row0 = N0 + chunk * 64;           // w-row  = k block (live)
        col0 = N0 + ntile * 64;           // w-col  = n block (live)
    }
    const int rr = tid >> 2, c0 = (tid & 3) * 16;
    const float* src = w + (size_t)(row0 + rr) * N_DIM + col0 + c0;
#pragma unroll
    for (int i = 0; i < 16; i += 4)
        *(float4*)&tile[rr][c0 + i] = *(const float4*)(src + i);
    __syncthreads();
    ushort_t loc[16];
#pragma unroll
    for (int i = 0; i < 16; ++i) {
        const int p = tid * 16 + i;
        const int s = p >> 9, e = p & 511;
        const int r = ((s >> 1) << 4) | ((e >> 3) & 15);
        const int c = ((s & 1) << 5) | (((e >> 7) & 3) << 3) | (e & 7);
        loc[i] = f2bf(tr ? tile[c][r] : tile[r][c]);
    }
    *(uint4*)&dst[tid * 16]     = *(uint4*)&loc[0];
    *(uint4*)&dst[tid * 16 + 8] = *(uint4*)&loc[8];
}

// --- init: x -> d_out (row-major) and t_pk [4 mtile][64 chunk][4096] --------
__global__ __launch_bounds__(256) void pack_t_init(const float* __restrict__ xin,
                                                   float* __restrict__ xout,
                                                   ushort_t* __restrict__ tpk) {
    __shared__ float tile[64][68];
    const int tid  = threadIdx.x;
    const int bid  = blockIdx.x;          // mtile*64 + chunk
    const int row0 = (bid >> 6) * 64;
    const int col0 = (bid & 63) * 64;
    const int rr = tid >> 2, c0 = (tid & 3) * 16;
    const size_t sidx = (size_t)(row0 + rr) * N_DIM + col0 + c0;
#pragma unroll
    for (int i = 0; i < 16; i += 4) {
        float4 v = *(const float4*)(xin + sidx + i);
        *(float4*)(xout + sidx + i) = v;
        tile[rr][c0 + i + 0] = tanhf(v.x);
        tile[rr][c0 + i + 1] = tanhf(v.y);
        tile[rr][c0 + i + 2] = tanhf(v.z);
        tile[rr][c0 + i + 3] = tanhf(v.w);
    }
    __syncthreads();
    ushort_t loc[16];
    ushort_t* dst = tpk + (size_t)bid * 4096;
#pragma unroll
    for (int i = 0; i < 16; ++i) {
        const int p = tid * 16 + i;
        const int s = p >> 9, e = p & 511;
        const int r = ((s >> 1) << 4) | ((e >> 3) & 15);
        const int c = ((s & 1) << 5) | (((e >> 7) & 3) << 3) | (e & 7);
        loc[i] = f2bf(tile[r][c]);
    }
    *(uint4*)&dst[tid * 16]     = *(uint4*)&loc[0];
    *(uint4*)&dst[tid * 16 + 8] = *(uint4*)&loc[8];
}

// --- one-time: mu0 = tanh(x_sensory) @ w_sensory^T  (k = chunks 0..11) ------
__global__ __launch_bounds__(256) void gemm_mu0(const ushort_t* __restrict__ Apk,
                                                const ushort_t* __restrict__ Bpk,
                                                float* __restrict__ mu0) {
    __shared__ __align__(16) ushort_t As[2][4096];
    __shared__ __align__(16) ushort_t Bs[2][4096];
    const int tid  = threadIdx.x;
    const int lane = tid & 63;
    const int wid  = tid >> 6;
    const int wave_m = wid >> 1, wave_n = wid & 1;
    const int ntile = blockIdx.x, mtile = blockIdx.y;

    const ushort_t* Ab = Apk + (size_t)mtile * 64 * 4096;
    const ushort_t* Bb = Bpk + (size_t)ntile * 64 * 4096;

    auto stage = [&](int buf, int kt) {
#pragma unroll
        for (int u = 0; u < 2; ++u) {
            const int off = (wid * 2 + u) * 512 + lane * 8;
            async_copy16(Ab + (size_t)kt * 4096 + off, &As[buf][off]);
            async_copy16(Bb + (size_t)kt * 4096 + off, &Bs[buf][off]);
        }
    };
    f32x4 acc[2][2] = {};
    auto compute = [&](int buf) {
#pragma unroll
        for (int ks = 0; ks < 2; ++ks) {
            bf16x8 a[2], b[2];
#pragma unroll
            for (int i = 0; i < 2; ++i) {
                const int asub = (wave_m * 2 + i) * 2 + ks;
                const int bsub = (wave_n * 2 + i) * 2 + ks;
                a[i] = *(const bf16x8*)(&As[buf][asub * 512 + lane * 8]);
                b[i] = *(const bf16x8*)(&Bs[buf][bsub * 512 + lane * 8]);
            }
#pragma unroll
            for (int i = 0; i < 2; ++i)
#pragma unroll
                for (int j = 0; j < 2; ++j)
                    acc[i][j] = __builtin_amdgcn_mfma_f32_16x16x32_bf16(
                        a[i], b[j], acc[i][j], 0, 0, 0);
        }
    };
    stage(0, 0);
    __syncthreads();
    for (int kt = 0; kt < 12; ++kt) {          // sensory chunks 0..11
        if (kt + 1 < 12) stage((kt + 1) & 1, kt + 1);
        compute(kt & 1);
        __syncthreads();
    }
    const int l15 = lane & 15, quad = lane >> 4;
#pragma unroll
    for (int j = 0; j < 2; ++j) {
        const int nl = ntile * 64 + wave_n * 32 + j * 16 + l15;
#pragma unroll
        for (int i = 0; i < 2; ++i)
#pragma unroll
            for (int r = 0; r < 4; ++r) {
                const int m = mtile * 64 + wave_m * 32 + i * 16 + quad * 4 + r;
                mu0[(size_t)m * N_LIVE + nl] = acc[i][j][r];
            }
    }
}

// --- cvt1 (after GEMM1): mu = mu0 + sum partials; e -> e_pk (GEMM2 A) -------
__global__ void cvt1(const float* __restrict__ xbuf,
                     const ushort_t* __restrict__ part,
                     const float* __restrict__ mu0,
                     ushort_t* __restrict__ epk,
                     const int* __restrict__ mask) {
    const int b  = blockIdx.y;
    const int nl = blockIdx.x * 256 + threadIdx.x;
    const size_t il = (size_t)b * N_LIVE + nl;
    float mu = mu0[il];
#pragma unroll
    for (int z = 0; z < KSPLIT; ++z)
        mu += bf2f(part[(size_t)z * (B_DIM * N_LIVE) + il]);
    const float x = xbuf[(size_t)b * N_DIM + N0 + nl];
    const float e = (x - mu) * (float)mask[N0 + nl];
    epk[((size_t)((b >> 6) * NCHL + (nl >> 6))) * 4096 + pkidx(b & 63, nl & 63)]
        = f2bf(e);
}

// --- cvt2 (after GEMM2): g = sum partials; x update; refresh t_pk -----------
__global__ void cvt2(float* __restrict__ xbuf,
                     const ushort_t* __restrict__ part,
                     const ushort_t* __restrict__ epk,
                     ushort_t* __restrict__ tpk,
                     const int* __restrict__ mask) {
    const int b  = blockIdx.y;
    const int nl = blockIdx.x * 256 + threadIdx.x;
    const size_t ix = (size_t)b * N_DIM + N0 + nl;
    float g = 0.0f;
#pragma unroll
    for (int z = 0; z < KSPLIT; ++z)
        g += bf2f(part[(size_t)z * (B_DIM * N_LIVE) + (size_t)b * N_LIVE + nl]);
    const float x  = xbuf[ix];
    const float th = tanhf(x);
    const float e  = bf2f(epk[((size_t)((b >> 6) * NCHL + (nl >> 6))) * 4096
                              + pkidx(b & 63, nl & 63)]);
    const float m  = (float)mask[N0 + nl];
    const float xn = x - LR_X * m * (e - (1.0f - th * th) * g);
    xbuf[ix] = xn;
    const int k = N0 + nl;                    // live k chunk = 12 + (nl>>6)
    tpk[((size_t)((b >> 6) * 64 + (k >> 6))) * 4096 + pkidx(b & 63, k & 63)]
        = f2bf(tanhf(xn));
}

// --- split-K GEMM, 128x128 tiles, 8 waves, XCD-pinned ntile-pairs -----------
// Apk: [4 mchunk][SA kchunk][4096], Bpk: [52 nchunk][SB kchunk][4096].
// Block = (nt2, mt2, z): output rows mt2*128..+127, cols nt2*128..+127.
// Per k-iter stages 4 linear 8KB chunks (A: mchunks 2*mt2,2*mt2+1; B:
// nchunks 2*nt2,2*nt2+1) = 32KB; 512 threads x 16B cover one chunk each.
// 8 waves in 2(M) x 4(N) grid; each wave computes 64x32 (acc[4][2]).
// 1-D grid of 512; xcd = bid&7: xcd<2 own 4 ntile-pairs, rest own 3
// (26 = 2*4 + 6*3); 16 slots (2 mt2 x 8 z) per pair; surplus returns early.
// Per-XCD B footprint <= 4 pairs x 832KB = 3.3MB < 4MiB L2, map stable
// across steps. k-chunks used: CO..CO+51 (CO=12 skips sensory for GEMM1).
template <int SA, int SB, int CO>
__global__ __launch_bounds__(512) void gemm_split(
    const ushort_t* __restrict__ Apk,
    const ushort_t* __restrict__ Bpk,
    ushort_t* __restrict__ part) {
    __shared__ __align__(16) ushort_t As[2][2 * 4096];   // 16 KB x2
    __shared__ __align__(16) ushort_t Bs[2][2 * 4096];   // 16 KB x2

    const int bid = blockIdx.x;
    const int xcd = bid & 7;
    const int i   = bid >> 3;                 // 0..63
    const int nloc = (xcd < 2) ? 4 : 3;
    if (i >= nloc * 16) return;
    const int p0   = (xcd < 2) ? xcd * 4 : 8 + (xcd - 2) * 3;
    const int nt2  = p0 + (i >> 4);           // 0..25
    const int mt2  = (i >> 3) & 1;            // 0..1
    const int z    = i & 7;                   // 0..7

    const int tid    = threadIdx.x;
    const int lane   = tid & 63;
    const int wid    = tid >> 6;       // 0..7
    const int wave_m = wid >> 2;       // 0..1 -> A chunk (64-row band)
    const int wave_n = wid & 3;        // 0..3 -> 32-col band
    const int wbc    = wave_n >> 1;    // B chunk (0/1)
    const int wbh    = wave_n & 1;     // 32-col half within chunk

    // uneven split-K of 52: z<4 -> 7 iters, z>=4 -> 6 iters
    const int kiters = 6 + (z < 4 ? 1 : 0);
    const int chbase = z * 6 + (z < 4 ? z : 4);

    ushort_t* pout = part + (size_t)z * (B_DIM * N_LIVE);
    const ushort_t* Ab = Apk + ((size_t)(mt2 * 2) * SA + CO + chbase) * 4096;
    const ushort_t* Bb = Bpk + ((size_t)(nt2 * 2) * SB + CO + chbase) * 4096;
    const int t8 = tid * 8;            // 512 threads x 16B = one 8KB chunk

    auto stage = [&](int buf, int kt) {
        async_copy16(Ab + (size_t)kt * 4096 + t8,              &As[buf][t8]);
        async_copy16(Ab + ((size_t)SA + kt) * 4096 + t8,       &As[buf][4096 + t8]);
        async_copy16(Bb + (size_t)kt * 4096 + t8,              &Bs[buf][t8]);
        async_copy16(Bb + ((size_t)SB + kt) * 4096 + t8,       &Bs[buf][4096 + t8]);
    };

    f32x4 acc[4][2] = {};

    auto compute = [&](int buf) {
#pragma unroll
        for (int ks = 0; ks < 2; ++ks) {
            bf16x8 a[4], b[2];
#pragma unroll
            for (int i2 = 0; i2 < 4; ++i2)
                a[i2] = *(const bf16x8*)(&As[buf][wave_m * 4096
                                                  + (i2 * 2 + ks) * 512 + lane * 8]);
#pragma unroll
            for (int j = 0; j < 2; ++j)
                b[j] = *(const bf16x8*)(&Bs[buf][wbc * 4096
                                                 + ((wbh * 2 + j) * 2 + ks) * 512
                                                 + lane * 8]);
#pragma unroll
            for (int i2 = 0; i2 < 4; ++i2)
#pragma unroll
                for (int j = 0; j < 2; ++j)
                    acc[i2][j] = __builtin_amdgcn_mfma_f32_16x16x32_bf16(
                        a[i2], b[j], acc[i2][j], 0, 0, 0);
        }
    };

    stage(0, 0);
    __syncthreads();
    for (int kt = 0; kt < kiters; ++kt) {
        if (kt + 1 < kiters) stage((kt + 1) & 1, kt + 1);
        compute(kt & 1);
        __syncthreads();
    }

    // Epilogue: bf16 partial stores (row-major partials).
    // C/D layout (verified m89/m91): col = lane&15, row = quad*4+reg
    const int l15  = lane & 15;
    const int quad = lane >> 4;
#pragma unroll
    for (int j = 0; j < 2; ++j) {
        const int nl = nt2 * 128 + wbc * 64 + wbh * 32 + j * 16 + l15;
#pragma unroll
        for (int i2 = 0; i2 < 4; ++i2) {
#pragma unroll
            for (int r = 0; r < 4; ++r) {
                const int m = mt2 * 128 + wave_m * 64 + i2 * 16 + quad * 4 + r;
                pout[(size_t)m * N_LIVE + nl] = f2bf(acc[i2][j][r]);
            }
        }
    }
}

extern "C" void kernel_launch(void* const* d_in, const int* in_sizes, int n_in,
                              void* d_out, int out_size, void* d_ws, size_t ws_size,
                              hipStream_t stream) {
    const float* x_in  = (const float*)d_in[0];
    const float* w_in  = (const float*)d_in[1];
    const int*   mask  = (const int*)d_in[2];
    float*       xbuf  = (float*)d_out;          // state lives in d_out

    uint8_t* ws = (uint8_t*)d_ws;
    // ws layout (end @ 70,254,592 bytes; ws_size = 256 MiB per fillBuffer):
    ushort_t* w_pk  = (ushort_t*)(ws);                   // 52*64*4096*2 = 27,262,976
    ushort_t* wt_pk = (ushort_t*)(ws + 27262976);        // 52*52*4096*2 = 22,151,168
    ushort_t* t_pk  = (ushort_t*)(ws + 49414144);        //  4*64*4096*2 =  2,097,152
    ushort_t* e_pk  = (ushort_t*)(ws + 51511296);        //  4*52*4096*2 =  1,703,936
    ushort_t* part  = (ushort_t*)(ws + 53215232);        // 8*256*3328*2 = 13,631,488
    float*    mu0   = (float*)(ws + 66846720);           //  256*3328*4  =  3,407,872

    pack_w<<<dim3(52 * 64 + 52 * 52), 256, 0, stream>>>(w_in, w_pk, wt_pk);
    pack_t_init<<<dim3(4 * 64), 256, 0, stream>>>(x_in, xbuf, t_pk);
    gemm_mu0<<<dim3(52, 4), 256, 0, stream>>>(t_pk, w_pk, mu0);

    const dim3 cgrid(N_LIVE / 256, B_DIM);
    for (int t = 0; t < T_STEPS; ++t) {
        // GEMM1: part[z] = mu_live partial ; A = t_pk (chunks 12..63), B = w_pk
        gemm_split<64, 64, 12><<<512, 512, 0, stream>>>(t_pk, w_pk, part);
        cvt1<<<cgrid, 256, 0, stream>>>(xbuf, part, mu0, e_pk, mask);
        // GEMM2: part[z] = g partial ; A = e_pk (52 chunks), B = wt_pk
        gemm_split<52, 52, 0><<<512, 512, 0, stream>>>(e_pk, wt_pk, part);
        cvt2<<<cgrid, 256, 0, stream>>>(xbuf, part, e_pk, t_pk, mask);
    }
}

// Round 6
// 1032.090 us; speedup vs baseline: 1.3346x; 1.3346x over previous
//
#include <hip/hip_runtime.h>
#include <stdint.h>
#include <stddef.h>

// ---------------------------------------------------------------------------
// PCgraph: T=32 steps of
//   mu = tanh(x) @ w^T ; e = (x-mu)*m ; g = e @ w ;
//   x = x - 0.1*m*(e - (1-tanh(x)^2)*g)
// bf16 MFMA 16x16x32, fp32 accum. x state in d_out (fp32).
// Round 15: r14 fused structure with the staging-stride BUG FIXED.
// r14 failed (NaN): its stage() used per-lane LDS stride 32B (each thread
// copying 2 adjacent 16B segments). global_load_lds ignores the per-lane LDS
// address and writes wave-uniform-base + lane*16 (HW rule, m104/m108), so
// the two copies overlapped shifted by 16B and half of each chunk was never
// written -> garbage operands -> NaN. Fix: off = (u*256 + gtid)*8 -- lane
// stride exactly 16B, wave-uniform base per copy. All prior rounds had this
// property; r14's fused regrouping broke it.
// Structure (r14): 2 dispatches/step. Full-K blocks (52 ntile x 4 mtile =
// 208), 1024 threads = 4 k-groups x 4 waves, each group runs the proven
// 4-wave dbuf loop over 13 chunks (counted vmcnt(4), raw s_barrier,
// sched_barrier(0) pins ds_reads below the barrier); f32 cross-group
// reduction in reused LDS; fused cvt epilogue writes packed e_pk / t_pk
// chunks (one linear 8KB chunk per block) + xbuf. mu0 precompute kept.
// XCD-pinned ntiles (B panel <=2.9MB per XCD L2, map stable across steps).
// ws end @ 56,623,104 < 256 MiB.
// ---------------------------------------------------------------------------

#define N_DIM 4096
#define B_DIM 256
#define T_STEPS 32
#define LR_X 0.1f
#define N0 768                      // first live column (aligned down from 784)
#define N_LIVE 3328                 // 4096 - 768 = 52*64
#define NCHL 52                     // live k-chunks (both GEMMs)
#define KG 4                        // k-groups per block
#define KITG 13                     // chunks per group (52/4)

typedef unsigned short ushort_t;
using bf16x8 = __attribute__((ext_vector_type(8))) __bf16;
using f32x4  = __attribute__((ext_vector_type(4))) float;

__device__ __forceinline__ ushort_t f2bf(float f) {
    union { float f; unsigned int u; } v; v.f = f;
    unsigned int r = v.u + 0x7fffu + ((v.u >> 16) & 1u);   // RNE
    return (ushort_t)(r >> 16);
}
__device__ __forceinline__ float bf2f(ushort_t h) {
    union { unsigned int u; float f; } v; v.u = ((unsigned int)h) << 16;
    return v.f;
}

// fragment-order index of element (r, c) inside a 64x64 tile-chunk
// (matches the LDS layout the MFMA fragments read; verified rounds 0-13)
__device__ __forceinline__ int pkidx(int r, int c) {
    const int s = ((r >> 4) << 1) | ((c >> 5) & 1);
    return s * 512 + (r & 15) * 8 + (((c >> 3) & 3) << 7) + (c & 7);
}

__device__ __forceinline__ void async_copy16(const ushort_t* g, ushort_t* l) {
    __builtin_amdgcn_global_load_lds(
        (__attribute__((address_space(1))) void*)(g),
        (__attribute__((address_space(3))) void*)(l),
        16, 0, 0);
}

// --- pack w -> w_pk [52 ntile][64 chunk][4096]  (B of GEMM1: rows 768..4095)
//            -> wt_pk [52 ntile][52 chunk][4096] (B of GEMM2: w^T, live range)
__global__ __launch_bounds__(256) void pack_w(const float* __restrict__ w,
                                              ushort_t* __restrict__ wpk,
                                              ushort_t* __restrict__ wtpk) {
    __shared__ float tile[64][68];
    const int tid = threadIdx.x;
    const int bid = blockIdx.x;
    int row0, col0; ushort_t* dst; bool tr;
    if (bid < 52 * 64) {
        tr   = false;
        dst  = wpk + (size_t)bid * 4096;
        row0 = N0 + (bid >> 6) * 64;      // B-row (n) block
        col0 = (bid & 63) * 64;           // k block
    } else {
        const int b2 = bid - 52 * 64;
        tr   = true;
        dst  = wtpk + (size_t)b2 * 4096;
        const int ntile = b2 / 52, chunk = b2 - ntile * 52;
        row0 = N0 + chunk * 64;           // w-row  = k block (live)
        col0 = N0 + ntile * 64;           // w-col  = n block (live)
    }
    const int rr = tid >> 2, c0 = (tid & 3) * 16;
    const float* src = w + (size_t)(row0 + rr) * N_DIM + col0 + c0;
#pragma unroll
    for (int i = 0; i < 16; i += 4)
        *(float4*)&tile[rr][c0 + i] = *(const float4*)(src + i);
    __syncthreads();
    ushort_t loc[16];
#pragma unroll
    for (int i = 0; i < 16; ++i) {
        const int p = tid * 16 + i;
        const int s = p >> 9, e = p & 511;
        const int r = ((s >> 1) << 4) | ((e >> 3) & 15);
        const int c = ((s & 1) << 5) | (((e >> 7) & 3) << 3) | (e & 7);
        loc[i] = f2bf(tr ? tile[c][r] : tile[r][c]);
    }
    *(uint4*)&dst[tid * 16]     = *(uint4*)&loc[0];
    *(uint4*)&dst[tid * 16 + 8] = *(uint4*)&loc[8];
}

// --- init: x -> d_out (row-major) and t_pk [4 mtile][64 chunk][4096] --------
__global__ __launch_bounds__(256) void pack_t_init(const float* __restrict__ xin,
                                                   float* __restrict__ xout,
                                                   ushort_t* __restrict__ tpk) {
    __shared__ float tile[64][68];
    const int tid  = threadIdx.x;
    const int bid  = blockIdx.x;          // mtile*64 + chunk
    const int row0 = (bid >> 6) * 64;
    const int col0 = (bid & 63) * 64;
    const int rr = tid >> 2, c0 = (tid & 3) * 16;
    const size_t sidx = (size_t)(row0 + rr) * N_DIM + col0 + c0;
#pragma unroll
    for (int i = 0; i < 16; i += 4) {
        float4 v = *(const float4*)(xin + sidx + i);
        *(float4*)(xout + sidx + i) = v;
        tile[rr][c0 + i + 0] = tanhf(v.x);
        tile[rr][c0 + i + 1] = tanhf(v.y);
        tile[rr][c0 + i + 2] = tanhf(v.z);
        tile[rr][c0 + i + 3] = tanhf(v.w);
    }
    __syncthreads();
    ushort_t loc[16];
    ushort_t* dst = tpk + (size_t)bid * 4096;
#pragma unroll
    for (int i = 0; i < 16; ++i) {
        const int p = tid * 16 + i;
        const int s = p >> 9, e = p & 511;
        const int r = ((s >> 1) << 4) | ((e >> 3) & 15);
        const int c = ((s & 1) << 5) | (((e >> 7) & 3) << 3) | (e & 7);
        loc[i] = f2bf(tile[r][c]);
    }
    *(uint4*)&dst[tid * 16]     = *(uint4*)&loc[0];
    *(uint4*)&dst[tid * 16 + 8] = *(uint4*)&loc[8];
}

// --- one-time: mu0 = tanh(x_sensory) @ w_sensory^T  (k = chunks 0..11) ------
__global__ __launch_bounds__(256) void gemm_mu0(const ushort_t* __restrict__ Apk,
                                                const ushort_t* __restrict__ Bpk,
                                                float* __restrict__ mu0) {
    __shared__ __align__(16) ushort_t As[2][4096];
    __shared__ __align__(16) ushort_t Bs[2][4096];
    const int tid  = threadIdx.x;
    const int lane = tid & 63;
    const int wid  = tid >> 6;
    const int wave_m = wid >> 1, wave_n = wid & 1;
    const int ntile = blockIdx.x, mtile = blockIdx.y;

    const ushort_t* Ab = Apk + (size_t)mtile * 64 * 4096;
    const ushort_t* Bb = Bpk + (size_t)ntile * 64 * 4096;

    auto stage = [&](int buf, int kt) {
#pragma unroll
        for (int u = 0; u < 2; ++u) {
            const int off = (wid * 2 + u) * 512 + lane * 8;
            async_copy16(Ab + (size_t)kt * 4096 + off, &As[buf][off]);
            async_copy16(Bb + (size_t)kt * 4096 + off, &Bs[buf][off]);
        }
    };
    f32x4 acc[2][2] = {};
    auto compute = [&](int buf) {
#pragma unroll
        for (int ks = 0; ks < 2; ++ks) {
            bf16x8 a[2], b[2];
#pragma unroll
            for (int i = 0; i < 2; ++i) {
                const int asub = (wave_m * 2 + i) * 2 + ks;
                const int bsub = (wave_n * 2 + i) * 2 + ks;
                a[i] = *(const bf16x8*)(&As[buf][asub * 512 + lane * 8]);
                b[i] = *(const bf16x8*)(&Bs[buf][bsub * 512 + lane * 8]);
            }
#pragma unroll
            for (int i = 0; i < 2; ++i)
#pragma unroll
                for (int j = 0; j < 2; ++j)
                    acc[i][j] = __builtin_amdgcn_mfma_f32_16x16x32_bf16(
                        a[i], b[j], acc[i][j], 0, 0, 0);
        }
    };
    stage(0, 0);
    __syncthreads();
    for (int kt = 0; kt < 12; ++kt) {          // sensory chunks 0..11
        if (kt + 1 < 12) stage((kt + 1) & 1, kt + 1);
        compute(kt & 1);
        __syncthreads();
    }
    const int l15 = lane & 15, quad = lane >> 4;
#pragma unroll
    for (int j = 0; j < 2; ++j) {
        const int nl = ntile * 64 + wave_n * 32 + j * 16 + l15;
#pragma unroll
        for (int i = 0; i < 2; ++i)
#pragma unroll
            for (int r = 0; r < 4; ++r) {
                const int m = mtile * 64 + wave_m * 32 + i * 16 + quad * 4 + r;
                mu0[(size_t)m * N_LIVE + nl] = acc[i][j][r];
            }
    }
}

// --- fused full-K GEMM + cvt epilogue ---------------------------------------
// Apk: [4 mtile][SA chunk][4096], Bpk: [52 ntile][SB chunk][4096].
// 208 active blocks (52 ntile x 4 mtile), 1024 threads = 4 k-groups x 4
// waves. Group g: chunks CO+g*13 .. +12 into its own LDS dbuf, 4-wave
// compute (64x64 tile, acc[2][2]/wave). Counted-vmcnt loop:
//   stage(kt+1); vmcnt(4); s_barrier; sched_barrier; compute(kt); s_barrier
// keeps next tile's 4 loads in flight across the barrier. Then f32
// cross-group reduction in reused LDS (64x68 padded) and fused cvt epilogue:
//   PHASE 1: e = (x - (mu0 + sum))*mask          -> e_pk packed chunk
//   PHASE 2: xn = x - 0.1*m*(e - (1-tanh^2)*sum) -> xbuf + t_pk packed chunk
// Each block's packed output is exactly one linear 8KB chunk.
// STAGING RULE (r14 bug): every async_copy16 batch must have per-lane LDS
// stride EXACTLY 16B and wave-uniform base -- HW writes base + lane*16.
// XCD-pinned: xcd=bid&7; xcd<4 own 7 ntiles, else 6 (B panel <=2.9MB/L2).
template <int SA, int SB, int CO, int PHASE>
__global__ __launch_bounds__(1024) void gemm_fused(
    const ushort_t* __restrict__ Apk,
    const ushort_t* __restrict__ Bpk,
    float* __restrict__ xbuf,
    const float* __restrict__ mu0,
    const int* __restrict__ mask,
    ushort_t* __restrict__ epk,
    ushort_t* __restrict__ tpk) {
    __shared__ __align__(16) ushort_t smem[65536];   // 128 KB
    ushort_t* As = smem;                              // [g*2+buf][4096]
    ushort_t* Bs = smem + 32768;                      // [g*2+buf][4096]

    const int bid = blockIdx.x;
    const int xcd = bid & 7;
    const int i   = bid >> 3;                 // 0..31
    const int nloc = (xcd < 4) ? 7 : 6;
    if (i >= nloc * 4) return;
    const int n0    = (xcd < 4) ? xcd * 7 : 28 + (xcd - 4) * 6;
    const int ntile = n0 + (i >> 2);          // 0..51
    const int mtile = i & 3;                  // 0..3

    const int tid  = threadIdx.x;
    const int lane = tid & 63;
    const int g    = tid >> 8;                // k-group 0..3
    const int gtid = tid & 255;
    const int gw   = (tid >> 6) & 3;          // wave within group
    const int wave_m = gw >> 1, wave_n = gw & 1;

    const ushort_t* Ab = Apk + ((size_t)mtile * SA + CO + g * KITG) * 4096;
    const ushort_t* Bb = Bpk + ((size_t)ntile * SB + CO + g * KITG) * 4096;

    auto stage = [&](int buf, int kt) {
        const ushort_t* Ac = Ab + (size_t)kt * 4096;
        const ushort_t* Bc = Bb + (size_t)kt * 4096;
#pragma unroll
        for (int u = 0; u < 2; ++u) {
            // lane stride 16B, wave-uniform base (u*4096 + gw*1024 bytes)
            const int off = (u * 256 + gtid) * 8;
            async_copy16(Ac + off, &As[(g * 2 + buf) * 4096 + off]);
            async_copy16(Bc + off, &Bs[(g * 2 + buf) * 4096 + off]);
        }
    };

    f32x4 acc[2][2] = {};

    auto compute = [&](int buf) {
#pragma unroll
        for (int ks = 0; ks < 2; ++ks) {
            bf16x8 a[2], b[2];
#pragma unroll
            for (int i2 = 0; i2 < 2; ++i2) {
                const int asub = (wave_m * 2 + i2) * 2 + ks;
                const int bsub = (wave_n * 2 + i2) * 2 + ks;
                a[i2] = *(const bf16x8*)(&As[(g * 2 + buf) * 4096 + asub * 512 + lane * 8]);
                b[i2] = *(const bf16x8*)(&Bs[(g * 2 + buf) * 4096 + bsub * 512 + lane * 8]);
            }
#pragma unroll
            for (int i2 = 0; i2 < 2; ++i2)
#pragma unroll
                for (int j = 0; j < 2; ++j)
                    acc[i2][j] = __builtin_amdgcn_mfma_f32_16x16x32_bf16(
                        a[i2], b[j], acc[i2][j], 0, 0, 0);
        }
    };

    // ---- k-loop: counted-vmcnt, raw barriers (4 loads/thread per stage) ----
    stage(0, 0);
    for (int kt = 0; kt < KITG; ++kt) {
        if (kt + 1 < KITG) {
            stage((kt + 1) & 1, kt + 1);
            asm volatile("s_waitcnt vmcnt(4)" ::: "memory");
        } else {
            asm volatile("s_waitcnt vmcnt(0)" ::: "memory");
        }
        __builtin_amdgcn_s_barrier();
        __builtin_amdgcn_sched_barrier(0);
        compute(kt & 1);
        __builtin_amdgcn_s_barrier();   // all ds_reads of this buf consumed
    }
    __syncthreads();                     // repurpose LDS for reduction

    // ---- cross-group f32 reduction: red[g] = 64x68-padded f32 tile ---------
    float* red = (float*)smem;           // 4 x 64*68*4B = 69.6 KB
    const int RP = 64 * 68;
    {
        const int l15 = lane & 15, quad = lane >> 4;
#pragma unroll
        for (int j = 0; j < 2; ++j) {
            const int col = wave_n * 32 + j * 16 + l15;
#pragma unroll
            for (int i2 = 0; i2 < 2; ++i2)
#pragma unroll
                for (int r = 0; r < 4; ++r) {
                    const int row = wave_m * 32 + i2 * 16 + quad * 4 + r;
                    red[g * RP + row * 68 + col] = acc[i2][j][r];
                }
        }
    }
    __syncthreads();

    // ---- fused epilogue: thread owns 4 consecutive packed positions --------
    const int p4 = tid * 4;
    const int s  = p4 >> 9, e9 = p4 & 511;
    const int r  = ((s >> 1) << 4) | ((e9 >> 3) & 15);
    const int c  = ((s & 1) << 5) | (((e9 >> 7) & 3) << 3) | (e9 & 7);

    float4 sv = *(const float4*)&red[0 * RP + r * 68 + c];
#pragma unroll
    for (int gg = 1; gg < KG; ++gg) {
        float4 v = *(const float4*)&red[gg * RP + r * 68 + c];
        sv.x += v.x; sv.y += v.y; sv.z += v.z; sv.w += v.w;
    }

    const int grow = mtile * 64 + r;          // batch row
    const int gcl  = ntile * 64 + c;          // live col
    const size_t xi = (size_t)grow * N_DIM + N0 + gcl;
    float4 xv = *(const float4*)&xbuf[xi];
    int4   mk = *(const int4*)&mask[N0 + gcl];

    if (PHASE == 1) {
        float4 m0 = *(const float4*)&mu0[(size_t)grow * N_LIVE + gcl];
        ushort_t ev[4];
        ev[0] = f2bf((xv.x - (m0.x + sv.x)) * (float)mk.x);
        ev[1] = f2bf((xv.y - (m0.y + sv.y)) * (float)mk.y);
        ev[2] = f2bf((xv.z - (m0.z + sv.z)) * (float)mk.z);
        ev[3] = f2bf((xv.w - (m0.w + sv.w)) * (float)mk.w);
        *(uint2*)&epk[((size_t)(mtile * NCHL + ntile)) * 4096 + p4]
            = *(uint2*)&ev[0];
    } else {
        // e read back through Apk (Apk IS e_pk in phase 2; same packed chunk)
        const ushort_t* ech = Apk + ((size_t)(mtile * SA + ntile)) * 4096;
        ushort_t ein[4];
        *(uint2*)&ein[0] = *(const uint2*)&ech[p4];
        float xn[4]; ushort_t tv[4];
        const float* svp = &sv.x;
        const int*   mkp = &mk.x;
        const float* xvp = &xv.x;
#pragma unroll
        for (int q = 0; q < 4; ++q) {
            const float x  = xvp[q];
            const float th = tanhf(x);
            const float ee = bf2f(ein[q]);
            xn[q] = x - LR_X * (float)mkp[q] * (ee - (1.0f - th * th) * svp[q]);
            tv[q] = f2bf(tanhf(xn[q]));
        }
        *(float4*)&xbuf[xi] = make_float4(xn[0], xn[1], xn[2], xn[3]);
        *(uint2*)&tpk[((size_t)(mtile * 64 + 12 + ntile)) * 4096 + p4]
            = *(uint2*)&tv[0];
    }
}

extern "C" void kernel_launch(void* const* d_in, const int* in_sizes, int n_in,
                              void* d_out, int out_size, void* d_ws, size_t ws_size,
                              hipStream_t stream) {
    const float* x_in  = (const float*)d_in[0];
    const float* w_in  = (const float*)d_in[1];
    const int*   mask  = (const int*)d_in[2];
    float*       xbuf  = (float*)d_out;          // state lives in d_out

    uint8_t* ws = (uint8_t*)d_ws;
    // ws layout (end @ 56,623,104 bytes; ws_size = 256 MiB per fillBuffer):
    ushort_t* w_pk  = (ushort_t*)(ws);                   // 52*64*4096*2 = 27,262,976
    ushort_t* wt_pk = (ushort_t*)(ws + 27262976);        // 52*52*4096*2 = 22,151,168
    ushort_t* t_pk  = (ushort_t*)(ws + 49414144);        //  4*64*4096*2 =  2,097,152
    ushort_t* e_pk  = (ushort_t*)(ws + 51511296);        //  4*52*4096*2 =  1,703,936
    float*    mu0   = (float*)(ws + 53215232);           //  256*3328*4  =  3,407,872

    pack_w<<<dim3(52 * 64 + 52 * 52), 256, 0, stream>>>(w_in, w_pk, wt_pk);
    pack_t_init<<<dim3(4 * 64), 256, 0, stream>>>(x_in, xbuf, t_pk);
    gemm_mu0<<<dim3(52, 4), 256, 0, stream>>>(t_pk, w_pk, mu0);

    for (int t = 0; t < T_STEPS; ++t) {
        // GEMM1+cvt1: e = (x - mu)*mask -> e_pk   (A = t_pk, B = w_pk)
        gemm_fused<64, 64, 12, 1><<<256, 1024, 0, stream>>>(
            t_pk, w_pk, xbuf, mu0, mask, e_pk, t_pk);
        // GEMM2+cvt2: x update -> xbuf, tanh -> t_pk (A = e_pk, B = wt_pk)
        gemm_fused<52, 52, 0, 2><<<256, 1024, 0, stream>>>(
            e_pk, wt_pk, xbuf, mu0, mask, e_pk, t_pk);
    }
}